// Round 1
// baseline (7190.186 us; speedup 1.0000x reference)
//
#include <hip/hip_runtime.h>

// Problem constants: B=32, T=128, I=H=O=512, L=2, proj width PW=1536 (xh 1024 | xr 512)
// ws layout (floats):
//   proj : [2][128][32][1536] = 12,582,912
//   seq  : [2][128][32][512]  =  4,194,304
//   hzero: [32][512]          =     16,384        total = 67.2 MB
#define PROJ_ELEMS 12582912
#define SEQ_ELEMS  4194304

// ---------------- proj GEMM: [8192 x 1536] = src @ [Wxh | Wxr] + bias ----------------
// grid (12, 64), block 256. 128x128 tile, 8x8 per-thread register tile.
__global__ __launch_bounds__(256)
void proj_kernel(const float* __restrict__ src,
                 const float* __restrict__ Wxh, const float* __restrict__ bxh,
                 const float* __restrict__ Wxr, const float* __restrict__ bxr,
                 float* __restrict__ proj, int layer)
{
    __shared__ float As[32][137];   // [k][row] transposed A tile
    __shared__ float Ws[32][132];   // [k][col]
    const int tid  = threadIdx.x;
    const int col0 = blockIdx.x * 128;
    const int row0 = blockIdx.y * 128;
    const int d    = row0 >> 12;              // rows 0..4095 = dir0, 4096..8191 = dir1
    const int ld   = layer * 2 + d;
    const int tx = tid & 15, ty = tid >> 4;

    const bool is_xr = (col0 >= 1024);
    const float* Wbase = is_xr ? (Wxr + (size_t)ld * 512 * 512 + (col0 - 1024))
                               : (Wxh + (size_t)ld * 512 * 1024 + col0);
    const int wstride = is_xr ? 512 : 1024;
    const float* bias = is_xr ? (bxr + ld * 512 + (col0 - 1024))
                              : (bxh + ld * 1024 + col0);

    float acc[8][8];
    #pragma unroll
    for (int i = 0; i < 8; i++)
        #pragma unroll
        for (int j = 0; j < 8; j++) acc[i][j] = 0.f;

    for (int k0 = 0; k0 < 512; k0 += 32) {
        // A tile: 128 rows x 32 k, stored transposed into LDS
        #pragma unroll
        for (int v = 0; v < 4; v++) {
            int idx = tid + v * 256;          // 0..1023 float4 slots
            int r   = idx >> 3;               // 0..127
            int c4  = (idx & 7) << 2;         // 0..28
            int gm  = row0 + r;
            int rr  = gm & 4095;
            int tt  = rr >> 5, bb = rr & 31;
            const float* p;
            if (layer == 0) {
                int ts = (gm >= 4096) ? (127 - tt) : tt;  // dir1 reads reversed time
                p = src + ((size_t)bb * 128 + ts) * 512 + (k0 + c4);
            } else {
                p = src + (((size_t)(gm >> 12) * 128 + tt) * 32 + bb) * 512 + (k0 + c4);
            }
            float4 vv = *(const float4*)p;
            As[c4 + 0][r] = vv.x; As[c4 + 1][r] = vv.y;
            As[c4 + 2][r] = vv.z; As[c4 + 3][r] = vv.w;
        }
        // W tile: 32 k x 128 cols
        #pragma unroll
        for (int v = 0; v < 4; v++) {
            int idx = tid + v * 256;
            int kr  = idx >> 5;               // 0..31
            int c4  = (idx & 31) << 2;        // 0..124
            *(float4*)&Ws[kr][c4] = *(const float4*)(Wbase + (size_t)(k0 + kr) * wstride + c4);
        }
        __syncthreads();
        #pragma unroll
        for (int kk = 0; kk < 32; kk++) {
            float a[8], w[8];
            *(float4*)&a[0] = *(const float4*)&As[kk][ty * 8];
            *(float4*)&a[4] = *(const float4*)&As[kk][ty * 8 + 4];
            *(float4*)&w[0] = *(const float4*)&Ws[kk][tx * 8];
            *(float4*)&w[4] = *(const float4*)&Ws[kk][tx * 8 + 4];
            #pragma unroll
            for (int i = 0; i < 8; i++)
                #pragma unroll
                for (int j = 0; j < 8; j++)
                    acc[i][j] += a[i] * w[j];
        }
        __syncthreads();
    }
    #pragma unroll
    for (int i = 0; i < 8; i++) {
        int gm = row0 + ty * 8 + i;
        float* dst = proj + (size_t)gm * 1536 + col0 + tx * 8;
        #pragma unroll
        for (int j = 0; j < 8; j++)
            dst[j] = acc[i][j] + bias[tx * 8 + j];
    }
}

// ---------------- GRU step: both dirs, one timestep ----------------
// grid 128 = d*64 + jg (8 cols each), block 256 = (b = tid>>3, jj = tid&7)
__global__ __launch_bounds__(256)
void step_kernel(const float* __restrict__ proj, float* __restrict__ seq,
                 const float* __restrict__ hzero,
                 const float* __restrict__ Whh, const float* __restrict__ bhh,
                 const float* __restrict__ Whr, const float* __restrict__ bhr,
                 int layer, int t)
{
    __shared__ float hs[32 * 512];  // h_prev staged as hs[b*512 + (k ^ ((b*4)&31))]
    const int tid = threadIdx.x;
    const int d   = blockIdx.x >> 6;
    const int jg  = blockIdx.x & 63;
    const int jj  = tid & 7;
    const int b   = tid >> 3;
    const int j   = jg * 8 + jj;
    const int ld  = layer * 2 + d;

    const float* hprev = (t == 0) ? hzero
                                  : (seq + ((size_t)(d * 128 + (t - 1)) * 32) * 512);

    #pragma unroll
    for (int v = 0; v < 16; v++) {
        int id = tid + v * 256;          // float4 index 0..4095
        int bl = id >> 7;                // 0..31
        int k4 = (id & 127) << 2;        // 0..508
        float4 vv = *(const float4*)(hprev + (size_t)bl * 512 + k4);
        int sw = (bl << 2) & 31;
        *(float4*)&hs[bl * 512 + (k4 ^ sw)] = vv;
    }
    __syncthreads();

    const float* wz = Whh + (size_t)ld * 512 * 1024 + j;   // z col j, stride 1024
    const float* wr = wz + 512;                            // r col 512+j
    const float* wg = Whr + (size_t)ld * 512 * 512 + j;    // g col j, stride 512
    const int sb = (b << 2) & 31;
    const float* hrow = hs + b * 512;

    float az = 0.f, ar = 0.f, ag = 0.f;
    #pragma unroll 4
    for (int k = 0; k < 512; k++) {
        float hv = hrow[k ^ sb];
        az += hv * wz[(size_t)k * 1024];
        ar += hv * wr[(size_t)k * 1024];
        ag += hv * wg[(size_t)k * 512];
    }

    const int pbase = ((d * 128 + t) * 32 + b) * 1536;
    float zpre = az + proj[pbase + j]       + bhh[ld * 1024 + j];
    float rpre = ar + proj[pbase + 512 + j] + bhh[ld * 1024 + 512 + j];
    float z = 1.f / (1.f + expf(-zpre));
    float r = 1.f / (1.f + expf(-rpre));
    float g = tanhf((ag + bhr[ld * 512 + j]) * r + proj[pbase + 1024 + j]);
    float hv_self = hrow[j ^ sb];
    float hn = z * hv_self + (1.f - z) * g;
    seq[((size_t)(d * 128 + t) * 32 + b) * 512 + j] = hn;
}

// ---------------- final FC: out[b][o] = cat[b][:] @ Wfc + bfc ----------------
// grid 64, block 256: one output per thread (b uniform per block -> scalar cat loads)
__global__ __launch_bounds__(256)
void fc_kernel(const float* __restrict__ seq, const float* __restrict__ Wfc,
               const float* __restrict__ bfc, float* __restrict__ out)
{
    int idx = blockIdx.x * 256 + threadIdx.x;   // 0..16383
    int b = idx >> 9, o = idx & 511;
    const float* catf = seq + ((size_t)(0 * 128 + 127) * 32 + b) * 512;  // fwd, t=127
    const float* catr = seq + ((size_t)(1 * 128 + 0) * 32 + b) * 512;    // rev, t=0
    float acc = bfc[o];
    #pragma unroll 8
    for (int k = 0; k < 512; k++) acc += catf[k] * Wfc[(size_t)k * 512 + o];
    #pragma unroll 8
    for (int k = 0; k < 512; k++) acc += catr[k] * Wfc[(size_t)(512 + k) * 512 + o];
    out[(size_t)b * 512 + o] = acc;
}

extern "C" void kernel_launch(void* const* d_in, const int* in_sizes, int n_in,
                              void* d_out, int out_size, void* d_ws, size_t ws_size,
                              hipStream_t stream) {
    (void)in_sizes; (void)n_in; (void)out_size; (void)ws_size;
    const float* x   = (const float*)d_in[0];
    const float* Wxh = (const float*)d_in[1];
    const float* bxh = (const float*)d_in[2];
    const float* Whh = (const float*)d_in[3];
    const float* bhh = (const float*)d_in[4];
    const float* Wxr = (const float*)d_in[5];
    const float* bxr = (const float*)d_in[6];
    const float* Whr = (const float*)d_in[7];
    const float* bhr = (const float*)d_in[8];
    const float* Wfc = (const float*)d_in[9];
    const float* bfc = (const float*)d_in[10];
    float* out  = (float*)d_out;
    float* ws   = (float*)d_ws;
    float* proj = ws;
    float* seq  = ws + PROJ_ELEMS;
    float* hz   = ws + PROJ_ELEMS + SEQ_ELEMS;

    hipMemsetAsync(hz, 0, 32 * 512 * sizeof(float), stream);

    dim3 pgrid(12, 64);
    // layer 0
    proj_kernel<<<pgrid, 256, 0, stream>>>(x, Wxh, bxh, Wxr, bxr, proj, 0);
    for (int t = 0; t < 128; t++)
        step_kernel<<<128, 256, 0, stream>>>(proj, seq, hz, Whh, bhh, Whr, bhr, 0, t);
    // layer 1 (input = layer-0 output sequence)
    proj_kernel<<<pgrid, 256, 0, stream>>>(seq, Wxh, bxh, Wxr, bxr, proj, 1);
    for (int t = 0; t < 128; t++)
        step_kernel<<<128, 256, 0, stream>>>(proj, seq, hz, Whh, bhh, Whr, bhr, 1, t);
    // head
    fc_kernel<<<64, 256, 0, stream>>>(seq, Wfc, bfc, out);
}